// Round 11
// baseline (664.908 us; speedup 1.0000x reference)
//
#include <hip/hip_runtime.h>

#define DEV __device__ __forceinline__

static const int NN = 100000;
static const int EE = 1000000;
static const int ECAP2 = 2048;   // staged edges per agg block (128 nodes, mean ~1280, 21 sigma headroom)

typedef unsigned int uv4 __attribute__((ext_vector_type(4)));
typedef float f32x4 __attribute__((ext_vector_type(4)));

DEV float bf2f(unsigned int h) {
    unsigned int u = h << 16;
    float f;
    __builtin_memcpy(&f, &u, 4);
    return f;
}
DEV unsigned short f2bf(float f) {  // round-to-nearest-even
    unsigned int u;
    __builtin_memcpy(&u, &f, 4);
    u = u + 0x7FFFu + ((u >> 16) & 1u);
    return (unsigned short)(u >> 16);
}
DEV unsigned int pk2(float a, float b) {
    return (unsigned int)f2bf(a) | ((unsigned int)f2bf(b) << 16);
}
DEV float h2f(unsigned short us) {
    _Float16 h;
    __builtin_memcpy(&h, &us, 2);
    return (float)h;
}
DEV unsigned short f2h(float f) {  // f32 -> fp16 bits (RTE)
    _Float16 h = (_Float16)f;
    unsigned short u;
    __builtin_memcpy(&u, &h, 2);
    return u;
}
DEV void unpack8(uint4 u, float* v) {  // 8 x bf16
    v[0] = bf2f(u.x & 0xffffu); v[1] = bf2f(u.x >> 16);
    v[2] = bf2f(u.y & 0xffffu); v[3] = bf2f(u.y >> 16);
    v[4] = bf2f(u.z & 0xffffu); v[5] = bf2f(u.z >> 16);
    v[6] = bf2f(u.w & 0xffffu); v[7] = bf2f(u.w >> 16);
}
DEV void unpack8h(uint4 u, float* v) {  // 8 x fp16
    v[0] = h2f((unsigned short)(u.x & 0xffffu)); v[1] = h2f((unsigned short)(u.x >> 16));
    v[2] = h2f((unsigned short)(u.y & 0xffffu)); v[3] = h2f((unsigned short)(u.y >> 16));
    v[4] = h2f((unsigned short)(u.z & 0xffffu)); v[5] = h2f((unsigned short)(u.z >> 16));
    v[6] = h2f((unsigned short)(u.w & 0xffffu)); v[7] = h2f((unsigned short)(u.w >> 16));
}
DEV void addh8(float* acc, uint4 u) {
    acc[0] += h2f((unsigned short)(u.x & 0xffffu)); acc[1] += h2f((unsigned short)(u.x >> 16));
    acc[2] += h2f((unsigned short)(u.y & 0xffffu)); acc[3] += h2f((unsigned short)(u.y >> 16));
    acc[4] += h2f((unsigned short)(u.z & 0xffffu)); acc[5] += h2f((unsigned short)(u.z >> 16));
    acc[6] += h2f((unsigned short)(u.w & 0xffffu)); acc[7] += h2f((unsigned short)(u.w >> 16));
}
DEV float take3(float v, int comp) {  // bf16 triple-split component
    float c0 = bf2f(f2bf(v));
    if (comp == 0) return c0;
    v -= c0;
    float c1 = bf2f(f2bf(v));
    if (comp == 1) return c1;
    return v - c1;   // pk2/f2bf at pack time rounds -> c2
}

// MFMA 16x16x32 bf16. Layouts (guide-verified m89/m91):
// A: m=l&15, k=(l>>4)*8+j;  B: n=l&15, k=(l>>4)*8+j;  D: col=l&15, row=(l>>4)*4+reg.
DEV void MF(f32x4& c, uv4 a, uv4 b) {
    asm("v_mfma_f32_16x16x32_bf16 %0, %1, %2, %0" : "+v"(c) : "v"(a), "v"(b));
}

// ---------------- CSR build (dual-graph via blockIdx.y) ----------------
// R9 lesson: returning device atomics in the fill path cost 2.3x vs this split
// count/fill scheme (count hides the atomic latency under massive TLP).
__global__ __launch_bounds__(256) void k_count_dual(const int* __restrict__ d0, const int* __restrict__ d1,
                                                    int* __restrict__ c0, int* __restrict__ c1,
                                                    int* __restrict__ p0, int* __restrict__ p1, int e) {
    int g = blockIdx.y;
    const int* dst = g ? d1 : d0;
    int* cnt = g ? c1 : c0;
    int* pos = g ? p1 : p0;
    int i = blockIdx.x * blockDim.x + threadIdx.x;
    if (i < e) pos[i] = atomicAdd(&cnt[dst[i]], 1);
}
__global__ __launch_bounds__(256) void k_scan_partial_dual(const int* __restrict__ c0, const int* __restrict__ c1,
                                                           int* __restrict__ p0, int* __restrict__ p1,
                                                           float* __restrict__ v0, float* __restrict__ v1, int n) {
    int g = blockIdx.y;
    const int* cnt = g ? c1 : c0;
    int* partial = g ? p1 : p0;
    float* dinv = g ? v1 : v0;
    __shared__ int lds[256];
    int base = blockIdx.x * 1024;
    int t = threadIdx.x;
    int s = 0;
#pragma unroll
    for (int i = 0; i < 4; i++) {
        int idx = base + t * 4 + i;
        int c = (idx < n) ? cnt[idx] : 0;
        if (idx < n) dinv[idx] = rsqrtf((float)c + 1.0f);
        s += c;
    }
    lds[t] = s;
    __syncthreads();
    for (int off = 128; off > 0; off >>= 1) {
        if (t < off) lds[t] += lds[t + off];
        __syncthreads();
    }
    if (t == 0) partial[blockIdx.x] = lds[0];
}
__global__ __launch_bounds__(256) void k_scan_write_dual(const int* __restrict__ c0, const int* __restrict__ c1,
                                                         const int* __restrict__ p0, const int* __restrict__ p1,
                                                         int* __restrict__ r0, int* __restrict__ r1,
                                                         int n, int total, int B) {
    int g = blockIdx.y;
    const int* cnt = g ? c1 : c0;
    const int* partial = g ? p1 : p0;
    int* rowptr = g ? r1 : r0;
    __shared__ int val[256];
    __shared__ int top[256];
    __shared__ int lds[256];
    __shared__ int base_s;
    int t = threadIdx.x;
    int pv = (t < B) ? partial[t] : 0;
    val[t] = pv;
    top[t] = pv;
    __syncthreads();
    for (int off = 1; off < 256; off <<= 1) {
        int x = (t >= off) ? top[t - off] : 0;
        __syncthreads();
        top[t] += x;
        __syncthreads();
    }
    if (t == 0) base_s = top[blockIdx.x] - val[blockIdx.x];
    __syncthreads();
    int base = blockIdx.x * 1024;
    int v[4];
    int s = 0;
#pragma unroll
    for (int i = 0; i < 4; i++) {
        int idx = base + t * 4 + i;
        v[i] = (idx < n) ? cnt[idx] : 0;
        s += v[i];
    }
    lds[t] = s;
    __syncthreads();
    int mine = s;
    for (int off = 1; off < 256; off <<= 1) {
        int x = (t >= off) ? lds[t - off] : 0;
        __syncthreads();
        lds[t] += x;
        __syncthreads();
    }
    int run = lds[t] - mine + base_s;
#pragma unroll
    for (int i = 0; i < 4; i++) {
        int idx = base + t * 4 + i;
        if (idx < n) rowptr[idx] = run;
        run += v[i];
    }
    if (blockIdx.x == 0 && t == 0) rowptr[n] = total;
}

// ---------------- conv weight fragments: bf16 TRIPLE split (R7 known-pass) ----------------
// 2^-16-class weight error is amplified by network gain (~468x) over budget; triple
// bf16 (c0+c1+c2, err ~2^-24) is proven safe (R7).
// Frag f, lane l: elem j = W[k=ks*32+(l>>4)*8+j][n=nt*16+(l&15)].
// Index: f = (layer*2+g)*24 + comp*8 + ks*4 + nt,  comp in {0,1,2}.
__global__ __launch_bounds__(64) void k_wfrag(const float* __restrict__ cf, const float* __restrict__ cs,
                                              uv4* __restrict__ WF) {
    int f = blockIdx.x, l = threadIdx.x;
    int lm = l & 15, kg = l >> 4;
    int set = f / 24;
    int layer = set >> 1, g = set & 1;
    int rest = f % 24;
    int comp = rest >> 3;
    int fi = rest & 7;
    int ks = fi >> 2, nt = fi & 3;
    const float* w = (g ? cs : cf) + layer * 4096;
    uv4 u;
#pragma unroll
    for (int d = 0; d < 4; d++) {
        float a = w[(ks * 32 + kg * 8 + 2 * d) * 64 + nt * 16 + lm];
        float b = w[(ks * 32 + kg * 8 + 2 * d + 1) * 64 + nt * 16 + lm];
        u[d] = pk2(take3(a, comp), take3(b, comp));
    }
    WF[(size_t)f * 64 + l] = u;
}

// ---------------- merged fill + encoder (independent work, one dispatch) ----------------
// Encoder output FEATURE-PLANAR [4][N][16] bf16, pre-scaled by dinv. No LDS (R3 lesson).
__global__ __launch_bounds__(256, 4) void k_fillenc_dual(
    const int* __restrict__ s0, const int* __restrict__ s1,
    const int* __restrict__ q0, const int* __restrict__ q1,
    const int* __restrict__ r0, const int* __restrict__ r1,
    int* __restrict__ col0, int* __restrict__ col1, int e,
    const float* __restrict__ x0, const float* __restrict__ x1,
    const float* __restrict__ w1a, const float* __restrict__ w1b,
    const float* __restrict__ b1a, const float* __restrict__ b1b,
    const float* __restrict__ w2a, const float* __restrict__ w2b,
    const float* __restrict__ b2a, const float* __restrict__ b2b,
    const float* __restrict__ v0, const float* __restrict__ v1,
    unsigned short* __restrict__ y0, unsigned short* __restrict__ y1,
    int n, int nbe, int nbr) {
    int bx = blockIdx.x;
    int t = threadIdx.x;
    if (bx < 2 * nbe) {
        // ---- fill path ----
        int g = (bx >= nbe) ? 1 : 0;
        const int* src = g ? s1 : s0;
        const int* dstv = src + e;
        const int* pos = g ? q1 : q0;
        const int* rowptr = g ? r1 : r0;
        int* col = g ? col1 : col0;
        int i = (bx - g * nbe) * 256 + t;
        if (i >= e) return;
        int s = src[i], d = dstv[i];
        col[rowptr[d] + pos[i]] = s;
        return;
    }
    // ---- enc path (register-bounded) ----
    int bx2 = bx - 2 * nbe;
    int g = (bx2 >= nbr) ? 1 : 0;
    const float* x = g ? x1 : x0;
    const float* w1 = g ? w1b : w1a;
    const float* b1 = g ? b1b : b1a;
    const float* w2 = g ? w2b : w2a;
    const float* b2 = g ? b2b : b2a;
    const float* dinv = g ? v1 : v0;
    unsigned short* out = g ? y1 : y0;
    int r = (bx2 - g * nbr) * 256 + t;
    if (r >= n) return;
    float4 xv = reinterpret_cast<const float4*>(x)[r];
    float xk[4] = {xv.x, xv.y, xv.z, xv.w};
    float d = dinv[r];
#pragma unroll 1
    for (int oc = 0; oc < 4; oc++) {
        float h2[16];
#pragma unroll
        for (int j = 0; j < 16; j++) h2[j] = b2[oc * 16 + j];
#pragma unroll 1
        for (int c = 0; c < 8; c++) {
            float h[8];
#pragma unroll
            for (int i = 0; i < 8; i++) h[i] = b1[c * 8 + i];
#pragma unroll
            for (int k = 0; k < 4; k++) {
#pragma unroll
                for (int i = 0; i < 8; i++) h[i] = fmaf(xk[k], w1[k * 64 + c * 8 + i], h[i]);
            }
#pragma unroll
            for (int i = 0; i < 8; i++) h[i] = fmaxf(h[i], 0.0f);
#pragma unroll
            for (int i = 0; i < 8; i++) {
                const float* wr = w2 + (c * 8 + i) * 64 + oc * 16;
#pragma unroll
                for (int j = 0; j < 16; j++) h2[j] = fmaf(h[i], wr[j], h2[j]);
            }
        }
        uint4 u0, u1;
        u0.x = pk2(h2[0] * d, h2[1] * d);   u0.y = pk2(h2[2] * d, h2[3] * d);
        u0.z = pk2(h2[4] * d, h2[5] * d);   u0.w = pk2(h2[6] * d, h2[7] * d);
        u1.x = pk2(h2[8] * d, h2[9] * d);   u1.y = pk2(h2[10] * d, h2[11] * d);
        u1.z = pk2(h2[12] * d, h2[13] * d); u1.w = pk2(h2[14] * d, h2[15] * d);
        unsigned short* ob = out + (size_t)oc * ((size_t)NN * 16) + (size_t)r * 16;
        *reinterpret_cast<uint4*>(ob) = u0;
        *reinterpret_cast<uint4*>(ob + 8) = u1;
    }
}

// ---------------- conv pass 1 (MFMA): t = h' @ W, fp16 IN-PLACE (R7 known-pass) ----------------
__global__ __launch_bounds__(256) void k_mmm(unsigned short* __restrict__ A0,
                                             unsigned short* __restrict__ A1,
                                             const uv4* __restrict__ WF,
                                             int fbase0, int nblk) {
    int bx = blockIdx.x;
    int g = (bx >= nblk) ? 1 : 0;
    unsigned short* A = g ? A1 : A0;
    const uv4* WB = WF + (size_t)(fbase0 + g * 24) * 64;
    int t = threadIdx.x, wave = t >> 6, l = t & 63, lm = l & 15, kg = l >> 4;
    int nodebase = (bx - g * nblk) * 64 + wave * 16;
    int node_l = nodebase + lm;
    if (node_l >= NN) node_l = NN - 1;
    uv4 a[2];
#pragma unroll
    for (int ks = 0; ks < 2; ks++) {
        int k = ks * 32 + kg * 8;
        a[ks] = *reinterpret_cast<const uv4*>(
            A + (size_t)(k >> 4) * ((size_t)NN * 16) + (size_t)node_l * 16 + ((k >> 3) & 1) * 8);
    }
    f32x4 acc[4];
#pragma unroll
    for (int nt = 0; nt < 4; nt++) acc[nt] = (f32x4){0.0f, 0.0f, 0.0f, 0.0f};
#pragma unroll
    for (int ks = 0; ks < 2; ks++) {
#pragma unroll
        for (int nt = 0; nt < 4; nt++) {
            uv4 c0 = WB[(size_t)(ks * 4 + nt) * 64 + l];
            uv4 c1 = WB[(size_t)(8 + ks * 4 + nt) * 64 + l];
            uv4 c2 = WB[(size_t)(16 + ks * 4 + nt) * 64 + l];
            MF(acc[nt], a[ks], c0);
            MF(acc[nt], a[ks], c1);
            MF(acc[nt], a[ks], c2);
        }
    }
#pragma unroll
    for (int r = 0; r < 4; r++) {
        int nd = nodebase + kg * 4 + r;
        if (nd < NN) {
#pragma unroll
            for (int nt = 0; nt < 4; nt++) {
                A[(size_t)nt * ((size_t)NN * 16) + (size_t)nd * 16 + lm] = f2h(acc[nt][r]);
            }
        }
    }
}

// ---------------- conv pass 2: L2-resident slice aggregation (unchanged, known-good) ----------------
__global__ __launch_bounds__(256) void k_agg_dual(
    const unsigned short* __restrict__ T0, const unsigned short* __restrict__ T1,
    const int* __restrict__ col0, const int* __restrict__ col1,
    const int* __restrict__ r0, const int* __restrict__ r1,
    const float* __restrict__ v0, const float* __restrict__ v1,
    const float* __restrict__ b0, const float* __restrict__ b1,
    unsigned short* __restrict__ y0, unsigned short* __restrict__ y1,
    int ntile, int scale_store) {
    int bx = blockIdx.x;
    int p = bx & 7;
    int g = p >> 2;
    int fs = p & 3;
    int lin = bx >> 3;
    if (lin >= ntile) return;
    const unsigned short* T = g ? T1 : T0;
    const int* col = g ? col1 : col0;
    const int* rowptr = g ? r1 : r0;
    const float* dinv = g ? v1 : v0;
    const float* b = g ? b1 : b0;
    unsigned short* y = g ? y1 : y0;

    __shared__ int eds[ECAP2];
    int t = threadIdx.x;
    int nl = t >> 1, h = t & 1;
    int nbase = lin * 128;
    int node = nbase + nl;
    bool act = node < NN;
    int nend = nbase + 128;
    if (nend > NN) nend = NN;

    const unsigned short* tp = T + (size_t)fs * ((size_t)NN * 16) + h * 8;

    float d = 0.0f;
    uint4 su = make_uint4(0, 0, 0, 0);
    if (act) {
        d = dinv[node];
        su = *reinterpret_cast<const uint4*>(tp + (size_t)node * 16);
    }
    int ebase = rowptr[nbase];
    int L = rowptr[nend] - ebase;
    int Ls = (L < ECAP2) ? L : ECAP2;
    for (int i = t; i < Ls; i += 256) {
        eds[i] = __builtin_nontemporal_load(col + ebase + i);
    }
    int e = 0, e1 = 0;
    if (act) {
        e = rowptr[node] - ebase;
        e1 = rowptr[node + 1] - ebase;
    }
    __syncthreads();

    if (act) {
        float acc[8];
        unpack8h(su, acc);
        if (e1 <= ECAP2) {
            for (; e + 8 <= e1; e += 8) {
                int s0 = eds[e + 0], s1 = eds[e + 1], s2 = eds[e + 2], s3 = eds[e + 3];
                int s4 = eds[e + 4], s5 = eds[e + 5], s6 = eds[e + 6], s7 = eds[e + 7];
                uint4 a0 = *reinterpret_cast<const uint4*>(tp + (size_t)s0 * 16);
                uint4 a1 = *reinterpret_cast<const uint4*>(tp + (size_t)s1 * 16);
                uint4 a2 = *reinterpret_cast<const uint4*>(tp + (size_t)s2 * 16);
                uint4 a3 = *reinterpret_cast<const uint4*>(tp + (size_t)s3 * 16);
                uint4 a4 = *reinterpret_cast<const uint4*>(tp + (size_t)s4 * 16);
                uint4 a5 = *reinterpret_cast<const uint4*>(tp + (size_t)s5 * 16);
                uint4 a6 = *reinterpret_cast<const uint4*>(tp + (size_t)s6 * 16);
                uint4 a7 = *reinterpret_cast<const uint4*>(tp + (size_t)s7 * 16);
                addh8(acc, a0); addh8(acc, a1); addh8(acc, a2); addh8(acc, a3);
                addh8(acc, a4); addh8(acc, a5); addh8(acc, a6); addh8(acc, a7);
            }
            if (e + 4 <= e1) {
                int s0 = eds[e + 0], s1 = eds[e + 1], s2 = eds[e + 2], s3 = eds[e + 3];
                uint4 a0 = *reinterpret_cast<const uint4*>(tp + (size_t)s0 * 16);
                uint4 a1 = *reinterpret_cast<const uint4*>(tp + (size_t)s1 * 16);
                uint4 a2 = *reinterpret_cast<const uint4*>(tp + (size_t)s2 * 16);
                uint4 a3 = *reinterpret_cast<const uint4*>(tp + (size_t)s3 * 16);
                addh8(acc, a0); addh8(acc, a1); addh8(acc, a2); addh8(acc, a3);
                e += 4;
            }
            if (e + 2 <= e1) {
                int s0 = eds[e + 0], s1 = eds[e + 1];
                uint4 a0 = *reinterpret_cast<const uint4*>(tp + (size_t)s0 * 16);
                uint4 a1 = *reinterpret_cast<const uint4*>(tp + (size_t)s1 * 16);
                addh8(acc, a0); addh8(acc, a1);
                e += 2;
            }
            if (e < e1) {
                int s0 = eds[e];
                uint4 a0 = *reinterpret_cast<const uint4*>(tp + (size_t)s0 * 16);
                addh8(acc, a0);
            }
        } else {
            for (; e < e1; e++) {
                int s0 = __builtin_nontemporal_load(col + ebase + e);
                uint4 a0 = *reinterpret_cast<const uint4*>(tp + (size_t)s0 * 16);
                addh8(acc, a0);
            }
        }
        const float* bb = b + fs * 16 + h * 8;
        float sc = scale_store ? d : 1.0f;
        float r[8];
#pragma unroll
        for (int i = 0; i < 8; i++) r[i] = fmaxf(fmaf(d, acc[i], bb[i]), 0.0f) * sc;
        uv4 ou;
        ou.x = pk2(r[0], r[1]); ou.y = pk2(r[2], r[3]);
        ou.z = pk2(r[4], r[5]); ou.w = pk2(r[6], r[7]);
        __builtin_nontemporal_store(
            ou, reinterpret_cast<uv4*>(y + (size_t)fs * ((size_t)NN * 16) + (size_t)node * 16 + h * 8));
    }
}

// ---------------- fused tail: scalar, full-h2 single pass ----------------
// Known-pass numerics (f32 weights via wave-uniform s_loads, f32 register math).
// R10 post-mortem: manual input prefetch DEFEATED compiler scheduling (96->117us);
// GEMM1 loops reverted to R7-exact. R11 change: GEMM2 computes all h2[64] in ONE
// k-pass -- w2 is then read fully sequentially (64B K$-lines fully consumed) with
// 64 independent FMAs per k, instead of the 8x c-chunked 32B-at-256B-stride pattern.
// Per-h2[j] FMA order unchanged -> bit-identical results.
__global__ __launch_bounds__(256) void k_tail(const unsigned short* __restrict__ F,
                                              const unsigned short* __restrict__ S,
                                              const float* __restrict__ w1, const float* __restrict__ b1,
                                              const float* __restrict__ w2, const float* __restrict__ b2,
                                              const float* __restrict__ ow, const float* __restrict__ ob,
                                              const float* __restrict__ cw, const float* __restrict__ cb,
                                              float* __restrict__ out, int n) {
    int r = blockIdx.x * blockDim.x + threadIdx.x;
    if (r >= n) return;
    float h1[64];
#pragma unroll
    for (int j = 0; j < 64; j++) h1[j] = b1[j];
#pragma unroll 1
    for (int k0 = 0; k0 < 8; k0++) {
        uint4 u = *reinterpret_cast<const uint4*>(
            F + (size_t)(k0 >> 1) * ((size_t)NN * 16) + (size_t)r * 16 + (k0 & 1) * 8);
        float v[8];
        unpack8(u, v);
        const float* wk = w1 + k0 * 8 * 64;
#pragma unroll
        for (int i = 0; i < 8; i++) {
#pragma unroll
            for (int j = 0; j < 64; j++) h1[j] = fmaf(v[i], wk[i * 64 + j], h1[j]);
        }
    }
#pragma unroll 1
    for (int k0 = 0; k0 < 8; k0++) {
        uint4 u = *reinterpret_cast<const uint4*>(
            S + (size_t)(k0 >> 1) * ((size_t)NN * 16) + (size_t)r * 16 + (k0 & 1) * 8);
        float v[8];
        unpack8(u, v);
        const float* wk = w1 + (64 + k0 * 8) * 64;
#pragma unroll
        for (int i = 0; i < 8; i++) {
#pragma unroll
            for (int j = 0; j < 64; j++) h1[j] = fmaf(v[i], wk[i * 64 + j], h1[j]);
        }
    }
#pragma unroll
    for (int j = 0; j < 64; j++) h1[j] = fmaxf(h1[j], 0.0f);

    // GEMM2: full h2[64], sequential w2 stream
    float h2[64];
#pragma unroll
    for (int j = 0; j < 64; j++) h2[j] = b2[j];
#pragma unroll 1
    for (int k = 0; k < 64; k++) {
        const float* wr = w2 + k * 64;
        float hk = h1[k];
#pragma unroll
        for (int j = 0; j < 64; j++) h2[j] = fmaf(hk, wr[j], h2[j]);
    }

    // GEMM3: heads, sequential ow/cw stream
    float nf[32];
#pragma unroll
    for (int j = 0; j < 32; j++) nf[j] = ob[j];
    float nt0 = cb[0], nt1 = cb[1];
#pragma unroll 1
    for (int kk = 0; kk < 64; kk++) {
        float hk = h2[kk];
        const float* wr = ow + kk * 32;
#pragma unroll
        for (int j = 0; j < 32; j++) nf[j] = fmaf(hk, wr[j], nf[j]);
        nt0 = fmaf(hk, cw[kk * 2 + 0], nt0);
        nt1 = fmaf(hk, cw[kk * 2 + 1], nt1);
    }
    float4* o = reinterpret_cast<float4*>(out + (size_t)r * 32);
#pragma unroll
    for (int c = 0; c < 8; c++) {
        o[c] = make_float4(nf[c * 4 + 0], nf[c * 4 + 1], nf[c * 4 + 2], nf[c * 4 + 3]);
    }
    float2* o2 = reinterpret_cast<float2*>(out + (size_t)NN * 32);
    o2[r] = make_float2(nt0, nt1);
}

extern "C" void kernel_launch(void* const* d_in, const int* in_sizes, int n_in,
                              void* d_out, int out_size, void* d_ws, size_t ws_size,
                              hipStream_t stream) {
    const int N = NN, E = EE;
    const float* front_x = (const float*)d_in[0];
    const float* side_x = (const float*)d_in[1];
    const int* fei = (const int*)d_in[2];
    const int* sei = (const int*)d_in[3];
    const float* fe_enc_w1 = (const float*)d_in[4];
    const float* fe_enc_b1 = (const float*)d_in[5];
    const float* fe_enc_w2 = (const float*)d_in[6];
    const float* fe_enc_b2 = (const float*)d_in[7];
    const float* fe_conv_w = (const float*)d_in[8];
    const float* fe_conv_b = (const float*)d_in[9];
    const float* se_enc_w1 = (const float*)d_in[10];
    const float* se_enc_b1 = (const float*)d_in[11];
    const float* se_enc_w2 = (const float*)d_in[12];
    const float* se_enc_b2 = (const float*)d_in[13];
    const float* se_conv_w = (const float*)d_in[14];
    const float* se_conv_b = (const float*)d_in[15];
    const float* fus_w1 = (const float*)d_in[16];
    const float* fus_b1 = (const float*)d_in[17];
    const float* fus_w2 = (const float*)d_in[18];
    const float* fus_b2 = (const float*)d_in[19];
    const float* out_w = (const float*)d_in[20];
    const float* out_b = (const float*)d_in[21];
    const float* cls_w = (const float*)d_in[22];
    const float* cls_b = (const float*)d_in[23];

    // workspace carve (256B aligned)
    char* ws = (char*)d_ws;
    size_t off = 0;
    auto take = [&](size_t bytes) -> char* {
        char* p = ws + off;
        off = (off + bytes + 255) & ~(size_t)255;
        return p;
    };
    int* zb = (int*)take((size_t)2 * N * 4);  // cnt0,cnt1 (zeroed)
    int* cnt0 = zb;
    int* cnt1 = zb + N;
    int* pos0 = (int*)take((size_t)E * 4);
    int* pos1 = (int*)take((size_t)E * 4);
    int* rp0 = (int*)take((size_t)(N + 1) * 4);
    int* rp1 = (int*)take((size_t)(N + 1) * 4);
    float* dv0 = (float*)take((size_t)N * 4);
    float* dv1 = (float*)take((size_t)N * 4);
    int* part0 = (int*)take(256 * 4);
    int* part1 = (int*)take(256 * 4);
    int* col0 = (int*)take((size_t)E * 4);
    int* col1 = (int*)take((size_t)E * 4);
    unsigned short* P0 = (unsigned short*)take((size_t)N * 64 * 2);
    unsigned short* P1 = (unsigned short*)take((size_t)N * 64 * 2);
    unsigned short* Q0 = (unsigned short*)take((size_t)N * 64 * 2);
    unsigned short* Q1 = (unsigned short*)take((size_t)N * 64 * 2);
    uv4* WF = (uv4*)take((size_t)144 * 64 * 16);   // 144 conv weight frags (triple bf16)

    const int NB_ROW = (N + 255) / 256;
    const int NB_E = (E + 255) / 256;
    const int NB_G = (N + 63) / 64;                // 1563 MFMA node-groups per graph
    const int NT_AGG = (N + 127) / 128;            // 782 agg tiles per (graph,slice)
    const int GA = NT_AGG * 8;                     // 8 XCD partitions
    const int SB = (N + 1023) / 1024;              // 98 partial blocks

    // ---- conv weight fragments (independent; launch first) ----
    k_wfrag<<<144, 64, 0, stream>>>(fe_conv_w, se_conv_w, WF);

    // ---- CSR build for both graphs ----
    hipMemsetAsync(zb, 0, (size_t)2 * N * 4, stream);
    k_count_dual<<<dim3(NB_E, 2), 256, 0, stream>>>(fei + E, sei + E, cnt0, cnt1, pos0, pos1, E);
    k_scan_partial_dual<<<dim3(SB, 2), 256, 0, stream>>>(cnt0, cnt1, part0, part1, dv0, dv1, N);
    k_scan_write_dual<<<dim3(SB, 2), 256, 0, stream>>>(cnt0, cnt1, part0, part1, rp0, rp1, N, E, SB);

    // ---- merged fill + encoders (planar output) ----
    k_fillenc_dual<<<2 * NB_E + 2 * NB_ROW, 256, 0, stream>>>(
        fei, sei, pos0, pos1, rp0, rp1, col0, col1, E,
        front_x, side_x, fe_enc_w1, se_enc_w1, fe_enc_b1, se_enc_b1,
        fe_enc_w2, se_enc_w2, fe_enc_b2, se_enc_b2, dv0, dv1, Q0, Q1,
        N, NB_E, NB_ROW);

    // ---- 3 conv layers = (MFMA transform, triple-bf16 W) + (L2-resident slice agg) ----
    // L1: Q -> P
    k_mmm<<<2 * NB_G, 256, 0, stream>>>(Q0, Q1, WF, 0 * 48, NB_G);
    k_agg_dual<<<GA, 256, 0, stream>>>(Q0, Q1, col0, col1, rp0, rp1, dv0, dv1,
                                       fe_conv_b + 0 * 64, se_conv_b + 0 * 64, P0, P1, NT_AGG, 1);
    // L2: P -> Q
    k_mmm<<<2 * NB_G, 256, 0, stream>>>(P0, P1, WF, 1 * 48, NB_G);
    k_agg_dual<<<GA, 256, 0, stream>>>(P0, P1, col0, col1, rp0, rp1, dv0, dv1,
                                       fe_conv_b + 1 * 64, se_conv_b + 1 * 64, Q0, Q1, NT_AGG, 1);
    // L3: Q -> P (no prescale; tail consumes planar)
    k_mmm<<<2 * NB_G, 256, 0, stream>>>(Q0, Q1, WF, 2 * 48, NB_G);
    k_agg_dual<<<GA, 256, 0, stream>>>(Q0, Q1, col0, col1, rp0, rp1, dv0, dv1,
                                       fe_conv_b + 2 * 64, se_conv_b + 2 * 64, P0, P1, NT_AGG, 0);

    // ---- fused fusion-MLP + heads (scalar, full-h2) ----
    k_tail<<<NB_ROW, 256, 0, stream>>>(P0, P1, fus_w1, fus_b1, fus_w2, fus_b2,
                                       out_w, out_b, cls_w, cls_b, (float*)d_out, N);
}

// Round 12
// 585.090 us; speedup vs baseline: 1.1364x; 1.1364x over previous
//
#include <hip/hip_runtime.h>

#define DEV __device__ __forceinline__

static const int NN = 100000;
static const int EE = 1000000;
static const int ECAP2 = 2048;   // staged edges per agg block (128 nodes, mean ~1280, 21 sigma headroom)

typedef unsigned int uv4 __attribute__((ext_vector_type(4)));
typedef float f32x4 __attribute__((ext_vector_type(4)));

DEV float bf2f(unsigned int h) {
    unsigned int u = h << 16;
    float f;
    __builtin_memcpy(&f, &u, 4);
    return f;
}
DEV unsigned short f2bf(float f) {  // round-to-nearest-even
    unsigned int u;
    __builtin_memcpy(&u, &f, 4);
    u = u + 0x7FFFu + ((u >> 16) & 1u);
    return (unsigned short)(u >> 16);
}
DEV unsigned int pk2(float a, float b) {
    return (unsigned int)f2bf(a) | ((unsigned int)f2bf(b) << 16);
}
DEV float h2f(unsigned short us) {
    _Float16 h;
    __builtin_memcpy(&h, &us, 2);
    return (float)h;
}
DEV unsigned short f2h(float f) {  // f32 -> fp16 bits (RTE)
    _Float16 h = (_Float16)f;
    unsigned short u;
    __builtin_memcpy(&u, &h, 2);
    return u;
}
DEV void unpack8(uint4 u, float* v) {  // 8 x bf16
    v[0] = bf2f(u.x & 0xffffu); v[1] = bf2f(u.x >> 16);
    v[2] = bf2f(u.y & 0xffffu); v[3] = bf2f(u.y >> 16);
    v[4] = bf2f(u.z & 0xffffu); v[5] = bf2f(u.z >> 16);
    v[6] = bf2f(u.w & 0xffffu); v[7] = bf2f(u.w >> 16);
}
DEV void unpack8h(uint4 u, float* v) {  // 8 x fp16
    v[0] = h2f((unsigned short)(u.x & 0xffffu)); v[1] = h2f((unsigned short)(u.x >> 16));
    v[2] = h2f((unsigned short)(u.y & 0xffffu)); v[3] = h2f((unsigned short)(u.y >> 16));
    v[4] = h2f((unsigned short)(u.z & 0xffffu)); v[5] = h2f((unsigned short)(u.z >> 16));
    v[6] = h2f((unsigned short)(u.w & 0xffffu)); v[7] = h2f((unsigned short)(u.w >> 16));
}
DEV void addh8(float* acc, uint4 u) {
    acc[0] += h2f((unsigned short)(u.x & 0xffffu)); acc[1] += h2f((unsigned short)(u.x >> 16));
    acc[2] += h2f((unsigned short)(u.y & 0xffffu)); acc[3] += h2f((unsigned short)(u.y >> 16));
    acc[4] += h2f((unsigned short)(u.z & 0xffffu)); acc[5] += h2f((unsigned short)(u.z >> 16));
    acc[6] += h2f((unsigned short)(u.w & 0xffffu)); acc[7] += h2f((unsigned short)(u.w >> 16));
}
DEV float take3(float v, int comp) {  // bf16 triple-split component
    float c0 = bf2f(f2bf(v));
    if (comp == 0) return c0;
    v -= c0;
    float c1 = bf2f(f2bf(v));
    if (comp == 1) return c1;
    return v - c1;   // pk2/f2bf at pack time rounds -> c2
}

// MFMA 16x16x32 bf16. Layouts (guide-verified m89/m91):
// A: m=l&15, k=(l>>4)*8+j;  B: n=l&15, k=(l>>4)*8+j;  D: col=l&15, row=(l>>4)*4+reg.
DEV void MF(f32x4& c, uv4 a, uv4 b) {
    asm("v_mfma_f32_16x16x32_bf16 %0, %1, %2, %0" : "+v"(c) : "v"(a), "v"(b));
}

// ---------------- CSR build (dual-graph via blockIdx.y) ----------------
// R9 lesson: returning device atomics in the fill path cost 2.3x vs this split
// count/fill scheme (count hides the atomic latency under massive TLP).
__global__ __launch_bounds__(256) void k_count_dual(const int* __restrict__ d0, const int* __restrict__ d1,
                                                    int* __restrict__ c0, int* __restrict__ c1,
                                                    int* __restrict__ p0, int* __restrict__ p1, int e) {
    int g = blockIdx.y;
    const int* dst = g ? d1 : d0;
    int* cnt = g ? c1 : c0;
    int* pos = g ? p1 : p0;
    int i = blockIdx.x * blockDim.x + threadIdx.x;
    if (i < e) pos[i] = atomicAdd(&cnt[dst[i]], 1);
}
__global__ __launch_bounds__(256) void k_scan_partial_dual(const int* __restrict__ c0, const int* __restrict__ c1,
                                                           int* __restrict__ p0, int* __restrict__ p1,
                                                           float* __restrict__ v0, float* __restrict__ v1, int n) {
    int g = blockIdx.y;
    const int* cnt = g ? c1 : c0;
    int* partial = g ? p1 : p0;
    float* dinv = g ? v1 : v0;
    __shared__ int lds[256];
    int base = blockIdx.x * 1024;
    int t = threadIdx.x;
    int s = 0;
#pragma unroll
    for (int i = 0; i < 4; i++) {
        int idx = base + t * 4 + i;
        int c = (idx < n) ? cnt[idx] : 0;
        if (idx < n) dinv[idx] = rsqrtf((float)c + 1.0f);
        s += c;
    }
    lds[t] = s;
    __syncthreads();
    for (int off = 128; off > 0; off >>= 1) {
        if (t < off) lds[t] += lds[t + off];
        __syncthreads();
    }
    if (t == 0) partial[blockIdx.x] = lds[0];
}
__global__ __launch_bounds__(256) void k_scan_write_dual(const int* __restrict__ c0, const int* __restrict__ c1,
                                                         const int* __restrict__ p0, const int* __restrict__ p1,
                                                         int* __restrict__ r0, int* __restrict__ r1,
                                                         int n, int total, int B) {
    int g = blockIdx.y;
    const int* cnt = g ? c1 : c0;
    const int* partial = g ? p1 : p0;
    int* rowptr = g ? r1 : r0;
    __shared__ int val[256];
    __shared__ int top[256];
    __shared__ int lds[256];
    __shared__ int base_s;
    int t = threadIdx.x;
    int pv = (t < B) ? partial[t] : 0;
    val[t] = pv;
    top[t] = pv;
    __syncthreads();
    for (int off = 1; off < 256; off <<= 1) {
        int x = (t >= off) ? top[t - off] : 0;
        __syncthreads();
        top[t] += x;
        __syncthreads();
    }
    if (t == 0) base_s = top[blockIdx.x] - val[blockIdx.x];
    __syncthreads();
    int base = blockIdx.x * 1024;
    int v[4];
    int s = 0;
#pragma unroll
    for (int i = 0; i < 4; i++) {
        int idx = base + t * 4 + i;
        v[i] = (idx < n) ? cnt[idx] : 0;
        s += v[i];
    }
    lds[t] = s;
    __syncthreads();
    int mine = s;
    for (int off = 1; off < 256; off <<= 1) {
        int x = (t >= off) ? lds[t - off] : 0;
        __syncthreads();
        lds[t] += x;
        __syncthreads();
    }
    int run = lds[t] - mine + base_s;
#pragma unroll
    for (int i = 0; i < 4; i++) {
        int idx = base + t * 4 + i;
        if (idx < n) rowptr[idx] = run;
        run += v[i];
    }
    if (blockIdx.x == 0 && t == 0) rowptr[n] = total;
}

// ---------------- conv weight fragments: bf16 TRIPLE split (R7 known-pass) ----------------
// 2^-16-class weight error is amplified by network gain (~468x) over budget; triple
// bf16 (c0+c1+c2, err ~2^-24) is proven safe (R7).
// Frag f, lane l: elem j = W[k=ks*32+(l>>4)*8+j][n=nt*16+(l&15)].
// Index: f = (layer*2+g)*24 + comp*8 + ks*4 + nt,  comp in {0,1,2}.
__global__ __launch_bounds__(64) void k_wfrag(const float* __restrict__ cf, const float* __restrict__ cs,
                                              uv4* __restrict__ WF) {
    int f = blockIdx.x, l = threadIdx.x;
    int lm = l & 15, kg = l >> 4;
    int set = f / 24;
    int layer = set >> 1, g = set & 1;
    int rest = f % 24;
    int comp = rest >> 3;
    int fi = rest & 7;
    int ks = fi >> 2, nt = fi & 3;
    const float* w = (g ? cs : cf) + layer * 4096;
    uv4 u;
#pragma unroll
    for (int d = 0; d < 4; d++) {
        float a = w[(ks * 32 + kg * 8 + 2 * d) * 64 + nt * 16 + lm];
        float b = w[(ks * 32 + kg * 8 + 2 * d + 1) * 64 + nt * 16 + lm];
        u[d] = pk2(take3(a, comp), take3(b, comp));
    }
    WF[(size_t)f * 64 + l] = u;
}

// ---------------- merged fill + encoder (independent work, one dispatch) ----------------
// Encoder output FEATURE-PLANAR [4][N][16] bf16, pre-scaled by dinv. No LDS (R3 lesson).
__global__ __launch_bounds__(256, 4) void k_fillenc_dual(
    const int* __restrict__ s0, const int* __restrict__ s1,
    const int* __restrict__ q0, const int* __restrict__ q1,
    const int* __restrict__ r0, const int* __restrict__ r1,
    int* __restrict__ col0, int* __restrict__ col1, int e,
    const float* __restrict__ x0, const float* __restrict__ x1,
    const float* __restrict__ w1a, const float* __restrict__ w1b,
    const float* __restrict__ b1a, const float* __restrict__ b1b,
    const float* __restrict__ w2a, const float* __restrict__ w2b,
    const float* __restrict__ b2a, const float* __restrict__ b2b,
    const float* __restrict__ v0, const float* __restrict__ v1,
    unsigned short* __restrict__ y0, unsigned short* __restrict__ y1,
    int n, int nbe, int nbr) {
    int bx = blockIdx.x;
    int t = threadIdx.x;
    if (bx < 2 * nbe) {
        // ---- fill path ----
        int g = (bx >= nbe) ? 1 : 0;
        const int* src = g ? s1 : s0;
        const int* dstv = src + e;
        const int* pos = g ? q1 : q0;
        const int* rowptr = g ? r1 : r0;
        int* col = g ? col1 : col0;
        int i = (bx - g * nbe) * 256 + t;
        if (i >= e) return;
        int s = src[i], d = dstv[i];
        col[rowptr[d] + pos[i]] = s;
        return;
    }
    // ---- enc path (register-bounded) ----
    int bx2 = bx - 2 * nbe;
    int g = (bx2 >= nbr) ? 1 : 0;
    const float* x = g ? x1 : x0;
    const float* w1 = g ? w1b : w1a;
    const float* b1 = g ? b1b : b1a;
    const float* w2 = g ? w2b : w2a;
    const float* b2 = g ? b2b : b2a;
    const float* dinv = g ? v1 : v0;
    unsigned short* out = g ? y1 : y0;
    int r = (bx2 - g * nbr) * 256 + t;
    if (r >= n) return;
    float4 xv = reinterpret_cast<const float4*>(x)[r];
    float xk[4] = {xv.x, xv.y, xv.z, xv.w};
    float d = dinv[r];
#pragma unroll 1
    for (int oc = 0; oc < 4; oc++) {
        float h2[16];
#pragma unroll
        for (int j = 0; j < 16; j++) h2[j] = b2[oc * 16 + j];
#pragma unroll 1
        for (int c = 0; c < 8; c++) {
            float h[8];
#pragma unroll
            for (int i = 0; i < 8; i++) h[i] = b1[c * 8 + i];
#pragma unroll
            for (int k = 0; k < 4; k++) {
#pragma unroll
                for (int i = 0; i < 8; i++) h[i] = fmaf(xk[k], w1[k * 64 + c * 8 + i], h[i]);
            }
#pragma unroll
            for (int i = 0; i < 8; i++) h[i] = fmaxf(h[i], 0.0f);
#pragma unroll
            for (int i = 0; i < 8; i++) {
                const float* wr = w2 + (c * 8 + i) * 64 + oc * 16;
#pragma unroll
                for (int j = 0; j < 16; j++) h2[j] = fmaf(h[i], wr[j], h2[j]);
            }
        }
        uint4 u0, u1;
        u0.x = pk2(h2[0] * d, h2[1] * d);   u0.y = pk2(h2[2] * d, h2[3] * d);
        u0.z = pk2(h2[4] * d, h2[5] * d);   u0.w = pk2(h2[6] * d, h2[7] * d);
        u1.x = pk2(h2[8] * d, h2[9] * d);   u1.y = pk2(h2[10] * d, h2[11] * d);
        u1.z = pk2(h2[12] * d, h2[13] * d); u1.w = pk2(h2[14] * d, h2[15] * d);
        unsigned short* ob = out + (size_t)oc * ((size_t)NN * 16) + (size_t)r * 16;
        *reinterpret_cast<uint4*>(ob) = u0;
        *reinterpret_cast<uint4*>(ob + 8) = u1;
    }
}

// ---------------- conv pass 1 (MFMA): t = h' @ W, fp16 IN-PLACE (R7 known-pass) ----------------
__global__ __launch_bounds__(256) void k_mmm(unsigned short* __restrict__ A0,
                                             unsigned short* __restrict__ A1,
                                             const uv4* __restrict__ WF,
                                             int fbase0, int nblk) {
    int bx = blockIdx.x;
    int g = (bx >= nblk) ? 1 : 0;
    unsigned short* A = g ? A1 : A0;
    const uv4* WB = WF + (size_t)(fbase0 + g * 24) * 64;
    int t = threadIdx.x, wave = t >> 6, l = t & 63, lm = l & 15, kg = l >> 4;
    int nodebase = (bx - g * nblk) * 64 + wave * 16;
    int node_l = nodebase + lm;
    if (node_l >= NN) node_l = NN - 1;
    uv4 a[2];
#pragma unroll
    for (int ks = 0; ks < 2; ks++) {
        int k = ks * 32 + kg * 8;
        a[ks] = *reinterpret_cast<const uv4*>(
            A + (size_t)(k >> 4) * ((size_t)NN * 16) + (size_t)node_l * 16 + ((k >> 3) & 1) * 8);
    }
    f32x4 acc[4];
#pragma unroll
    for (int nt = 0; nt < 4; nt++) acc[nt] = (f32x4){0.0f, 0.0f, 0.0f, 0.0f};
#pragma unroll
    for (int ks = 0; ks < 2; ks++) {
#pragma unroll
        for (int nt = 0; nt < 4; nt++) {
            uv4 c0 = WB[(size_t)(ks * 4 + nt) * 64 + l];
            uv4 c1 = WB[(size_t)(8 + ks * 4 + nt) * 64 + l];
            uv4 c2 = WB[(size_t)(16 + ks * 4 + nt) * 64 + l];
            MF(acc[nt], a[ks], c0);
            MF(acc[nt], a[ks], c1);
            MF(acc[nt], a[ks], c2);
        }
    }
#pragma unroll
    for (int r = 0; r < 4; r++) {
        int nd = nodebase + kg * 4 + r;
        if (nd < NN) {
#pragma unroll
            for (int nt = 0; nt < 4; nt++) {
                A[(size_t)nt * ((size_t)NN * 16) + (size_t)nd * 16 + lm] = f2h(acc[nt][r]);
            }
        }
    }
}

// ---------------- conv pass 2: L2-resident slice aggregation (unchanged, known-good) ----------------
__global__ __launch_bounds__(256) void k_agg_dual(
    const unsigned short* __restrict__ T0, const unsigned short* __restrict__ T1,
    const int* __restrict__ col0, const int* __restrict__ col1,
    const int* __restrict__ r0, const int* __restrict__ r1,
    const float* __restrict__ v0, const float* __restrict__ v1,
    const float* __restrict__ b0, const float* __restrict__ b1,
    unsigned short* __restrict__ y0, unsigned short* __restrict__ y1,
    int ntile, int scale_store) {
    int bx = blockIdx.x;
    int p = bx & 7;
    int g = p >> 2;
    int fs = p & 3;
    int lin = bx >> 3;
    if (lin >= ntile) return;
    const unsigned short* T = g ? T1 : T0;
    const int* col = g ? col1 : col0;
    const int* rowptr = g ? r1 : r0;
    const float* dinv = g ? v1 : v0;
    const float* b = g ? b1 : b0;
    unsigned short* y = g ? y1 : y0;

    __shared__ int eds[ECAP2];
    int t = threadIdx.x;
    int nl = t >> 1, h = t & 1;
    int nbase = lin * 128;
    int node = nbase + nl;
    bool act = node < NN;
    int nend = nbase + 128;
    if (nend > NN) nend = NN;

    const unsigned short* tp = T + (size_t)fs * ((size_t)NN * 16) + h * 8;

    float d = 0.0f;
    uint4 su = make_uint4(0, 0, 0, 0);
    if (act) {
        d = dinv[node];
        su = *reinterpret_cast<const uint4*>(tp + (size_t)node * 16);
    }
    int ebase = rowptr[nbase];
    int L = rowptr[nend] - ebase;
    int Ls = (L < ECAP2) ? L : ECAP2;
    for (int i = t; i < Ls; i += 256) {
        eds[i] = __builtin_nontemporal_load(col + ebase + i);
    }
    int e = 0, e1 = 0;
    if (act) {
        e = rowptr[node] - ebase;
        e1 = rowptr[node + 1] - ebase;
    }
    __syncthreads();

    if (act) {
        float acc[8];
        unpack8h(su, acc);
        if (e1 <= ECAP2) {
            for (; e + 8 <= e1; e += 8) {
                int s0 = eds[e + 0], s1 = eds[e + 1], s2 = eds[e + 2], s3 = eds[e + 3];
                int s4 = eds[e + 4], s5 = eds[e + 5], s6 = eds[e + 6], s7 = eds[e + 7];
                uint4 a0 = *reinterpret_cast<const uint4*>(tp + (size_t)s0 * 16);
                uint4 a1 = *reinterpret_cast<const uint4*>(tp + (size_t)s1 * 16);
                uint4 a2 = *reinterpret_cast<const uint4*>(tp + (size_t)s2 * 16);
                uint4 a3 = *reinterpret_cast<const uint4*>(tp + (size_t)s3 * 16);
                uint4 a4 = *reinterpret_cast<const uint4*>(tp + (size_t)s4 * 16);
                uint4 a5 = *reinterpret_cast<const uint4*>(tp + (size_t)s5 * 16);
                uint4 a6 = *reinterpret_cast<const uint4*>(tp + (size_t)s6 * 16);
                uint4 a7 = *reinterpret_cast<const uint4*>(tp + (size_t)s7 * 16);
                addh8(acc, a0); addh8(acc, a1); addh8(acc, a2); addh8(acc, a3);
                addh8(acc, a4); addh8(acc, a5); addh8(acc, a6); addh8(acc, a7);
            }
            if (e + 4 <= e1) {
                int s0 = eds[e + 0], s1 = eds[e + 1], s2 = eds[e + 2], s3 = eds[e + 3];
                uint4 a0 = *reinterpret_cast<const uint4*>(tp + (size_t)s0 * 16);
                uint4 a1 = *reinterpret_cast<const uint4*>(tp + (size_t)s1 * 16);
                uint4 a2 = *reinterpret_cast<const uint4*>(tp + (size_t)s2 * 16);
                uint4 a3 = *reinterpret_cast<const uint4*>(tp + (size_t)s3 * 16);
                addh8(acc, a0); addh8(acc, a1); addh8(acc, a2); addh8(acc, a3);
                e += 4;
            }
            if (e + 2 <= e1) {
                int s0 = eds[e + 0], s1 = eds[e + 1];
                uint4 a0 = *reinterpret_cast<const uint4*>(tp + (size_t)s0 * 16);
                uint4 a1 = *reinterpret_cast<const uint4*>(tp + (size_t)s1 * 16);
                addh8(acc, a0); addh8(acc, a1);
                e += 2;
            }
            if (e < e1) {
                int s0 = eds[e];
                uint4 a0 = *reinterpret_cast<const uint4*>(tp + (size_t)s0 * 16);
                addh8(acc, a0);
            }
        } else {
            for (; e < e1; e++) {
                int s0 = __builtin_nontemporal_load(col + ebase + e);
                uint4 a0 = *reinterpret_cast<const uint4*>(tp + (size_t)s0 * 16);
                addh8(acc, a0);
            }
        }
        const float* bb = b + fs * 16 + h * 8;
        float sc = scale_store ? d : 1.0f;
        float r[8];
#pragma unroll
        for (int i = 0; i < 8; i++) r[i] = fmaxf(fmaf(d, acc[i], bb[i]), 0.0f) * sc;
        uv4 ou;
        ou.x = pk2(r[0], r[1]); ou.y = pk2(r[2], r[3]);
        ou.z = pk2(r[4], r[5]); ou.w = pk2(r[6], r[7]);
        __builtin_nontemporal_store(
            ou, reinterpret_cast<uv4*>(y + (size_t)fs * ((size_t)NN * 16) + (size_t)node * 16 + h * 8));
    }
}

// ---------------- fused tail: R7-exact scalar (known-pass, 96us) ----------------
// f32 weights via wave-uniform s_loads, f32 register math, h2 in chunks of 8
// (R11 lesson: full h2[64] spills to scratch -- VGPR 40 + 450MB scratch writes).
__global__ __launch_bounds__(256) void k_tail(const unsigned short* __restrict__ F,
                                              const unsigned short* __restrict__ S,
                                              const float* __restrict__ w1, const float* __restrict__ b1,
                                              const float* __restrict__ w2, const float* __restrict__ b2,
                                              const float* __restrict__ ow, const float* __restrict__ ob,
                                              const float* __restrict__ cw, const float* __restrict__ cb,
                                              float* __restrict__ out, int n) {
    int r = blockIdx.x * blockDim.x + threadIdx.x;
    if (r >= n) return;
    float h1[64];
#pragma unroll
    for (int j = 0; j < 64; j++) h1[j] = b1[j];
#pragma unroll 1
    for (int k0 = 0; k0 < 8; k0++) {
        uint4 u = *reinterpret_cast<const uint4*>(
            F + (size_t)(k0 >> 1) * ((size_t)NN * 16) + (size_t)r * 16 + (k0 & 1) * 8);
        float v[8];
        unpack8(u, v);
        const float* wk = w1 + k0 * 8 * 64;
#pragma unroll
        for (int i = 0; i < 8; i++) {
#pragma unroll
            for (int j = 0; j < 64; j++) h1[j] = fmaf(v[i], wk[i * 64 + j], h1[j]);
        }
    }
#pragma unroll 1
    for (int k0 = 0; k0 < 8; k0++) {
        uint4 u = *reinterpret_cast<const uint4*>(
            S + (size_t)(k0 >> 1) * ((size_t)NN * 16) + (size_t)r * 16 + (k0 & 1) * 8);
        float v[8];
        unpack8(u, v);
        const float* wk = w1 + (64 + k0 * 8) * 64;
#pragma unroll
        for (int i = 0; i < 8; i++) {
#pragma unroll
            for (int j = 0; j < 64; j++) h1[j] = fmaf(v[i], wk[i * 64 + j], h1[j]);
        }
    }
#pragma unroll
    for (int j = 0; j < 64; j++) h1[j] = fmaxf(h1[j], 0.0f);

    float nf[32];
#pragma unroll
    for (int j = 0; j < 32; j++) nf[j] = ob[j];
    float nt0 = cb[0], nt1 = cb[1];
#pragma unroll 1
    for (int c = 0; c < 8; c++) {  // h2 in chunks of 8
        float h2[8];
#pragma unroll
        for (int i = 0; i < 8; i++) h2[i] = b2[c * 8 + i];
#pragma unroll
        for (int k = 0; k < 64; k++) {
            const float* wr = w2 + k * 64 + c * 8;
#pragma unroll
            for (int i = 0; i < 8; i++) h2[i] = fmaf(h1[k], wr[i], h2[i]);
        }
#pragma unroll
        for (int i = 0; i < 8; i++) {
            int kk = c * 8 + i;
#pragma unroll
            for (int j = 0; j < 32; j++) nf[j] = fmaf(h2[i], ow[kk * 32 + j], nf[j]);
            nt0 = fmaf(h2[i], cw[kk * 2 + 0], nt0);
            nt1 = fmaf(h2[i], cw[kk * 2 + 1], nt1);
        }
    }
    float4* o = reinterpret_cast<float4*>(out + (size_t)r * 32);
#pragma unroll
    for (int c = 0; c < 8; c++) {
        o[c] = make_float4(nf[c * 4 + 0], nf[c * 4 + 1], nf[c * 4 + 2], nf[c * 4 + 3]);
    }
    float2* o2 = reinterpret_cast<float2*>(out + (size_t)NN * 32);
    o2[r] = make_float2(nt0, nt1);
}

extern "C" void kernel_launch(void* const* d_in, const int* in_sizes, int n_in,
                              void* d_out, int out_size, void* d_ws, size_t ws_size,
                              hipStream_t stream) {
    const int N = NN, E = EE;
    const float* front_x = (const float*)d_in[0];
    const float* side_x = (const float*)d_in[1];
    const int* fei = (const int*)d_in[2];
    const int* sei = (const int*)d_in[3];
    const float* fe_enc_w1 = (const float*)d_in[4];
    const float* fe_enc_b1 = (const float*)d_in[5];
    const float* fe_enc_w2 = (const float*)d_in[6];
    const float* fe_enc_b2 = (const float*)d_in[7];
    const float* fe_conv_w = (const float*)d_in[8];
    const float* fe_conv_b = (const float*)d_in[9];
    const float* se_enc_w1 = (const float*)d_in[10];
    const float* se_enc_b1 = (const float*)d_in[11];
    const float* se_enc_w2 = (const float*)d_in[12];
    const float* se_enc_b2 = (const float*)d_in[13];
    const float* se_conv_w = (const float*)d_in[14];
    const float* se_conv_b = (const float*)d_in[15];
    const float* fus_w1 = (const float*)d_in[16];
    const float* fus_b1 = (const float*)d_in[17];
    const float* fus_w2 = (const float*)d_in[18];
    const float* fus_b2 = (const float*)d_in[19];
    const float* out_w = (const float*)d_in[20];
    const float* out_b = (const float*)d_in[21];
    const float* cls_w = (const float*)d_in[22];
    const float* cls_b = (const float*)d_in[23];

    // workspace carve (256B aligned)
    char* ws = (char*)d_ws;
    size_t off = 0;
    auto take = [&](size_t bytes) -> char* {
        char* p = ws + off;
        off = (off + bytes + 255) & ~(size_t)255;
        return p;
    };
    int* zb = (int*)take((size_t)2 * N * 4);  // cnt0,cnt1 (zeroed)
    int* cnt0 = zb;
    int* cnt1 = zb + N;
    int* pos0 = (int*)take((size_t)E * 4);
    int* pos1 = (int*)take((size_t)E * 4);
    int* rp0 = (int*)take((size_t)(N + 1) * 4);
    int* rp1 = (int*)take((size_t)(N + 1) * 4);
    float* dv0 = (float*)take((size_t)N * 4);
    float* dv1 = (float*)take((size_t)N * 4);
    int* part0 = (int*)take(256 * 4);
    int* part1 = (int*)take(256 * 4);
    int* col0 = (int*)take((size_t)E * 4);
    int* col1 = (int*)take((size_t)E * 4);
    unsigned short* P0 = (unsigned short*)take((size_t)N * 64 * 2);
    unsigned short* P1 = (unsigned short*)take((size_t)N * 64 * 2);
    unsigned short* Q0 = (unsigned short*)take((size_t)N * 64 * 2);
    unsigned short* Q1 = (unsigned short*)take((size_t)N * 64 * 2);
    uv4* WF = (uv4*)take((size_t)144 * 64 * 16);   // 144 conv weight frags (triple bf16)

    const int NB_ROW = (N + 255) / 256;
    const int NB_E = (E + 255) / 256;
    const int NB_G = (N + 63) / 64;                // 1563 MFMA node-groups per graph
    const int NT_AGG = (N + 127) / 128;            // 782 agg tiles per (graph,slice)
    const int GA = NT_AGG * 8;                     // 8 XCD partitions
    const int SB = (N + 1023) / 1024;              // 98 partial blocks

    // ---- conv weight fragments (independent; launch first) ----
    k_wfrag<<<144, 64, 0, stream>>>(fe_conv_w, se_conv_w, WF);

    // ---- CSR build for both graphs ----
    hipMemsetAsync(zb, 0, (size_t)2 * N * 4, stream);
    k_count_dual<<<dim3(NB_E, 2), 256, 0, stream>>>(fei + E, sei + E, cnt0, cnt1, pos0, pos1, E);
    k_scan_partial_dual<<<dim3(SB, 2), 256, 0, stream>>>(cnt0, cnt1, part0, part1, dv0, dv1, N);
    k_scan_write_dual<<<dim3(SB, 2), 256, 0, stream>>>(cnt0, cnt1, part0, part1, rp0, rp1, N, E, SB);

    // ---- merged fill + encoders (planar output) ----
    k_fillenc_dual<<<2 * NB_E + 2 * NB_ROW, 256, 0, stream>>>(
        fei, sei, pos0, pos1, rp0, rp1, col0, col1, E,
        front_x, side_x, fe_enc_w1, se_enc_w1, fe_enc_b1, se_enc_b1,
        fe_enc_w2, se_enc_w2, fe_enc_b2, se_enc_b2, dv0, dv1, Q0, Q1,
        N, NB_E, NB_ROW);

    // ---- 3 conv layers = (MFMA transform, triple-bf16 W) + (L2-resident slice agg) ----
    // L1: Q -> P
    k_mmm<<<2 * NB_G, 256, 0, stream>>>(Q0, Q1, WF, 0 * 48, NB_G);
    k_agg_dual<<<GA, 256, 0, stream>>>(Q0, Q1, col0, col1, rp0, rp1, dv0, dv1,
                                       fe_conv_b + 0 * 64, se_conv_b + 0 * 64, P0, P1, NT_AGG, 1);
    // L2: P -> Q
    k_mmm<<<2 * NB_G, 256, 0, stream>>>(P0, P1, WF, 1 * 48, NB_G);
    k_agg_dual<<<GA, 256, 0, stream>>>(P0, P1, col0, col1, rp0, rp1, dv0, dv1,
                                       fe_conv_b + 1 * 64, se_conv_b + 1 * 64, Q0, Q1, NT_AGG, 1);
    // L3: Q -> P (no prescale; tail consumes planar)
    k_mmm<<<2 * NB_G, 256, 0, stream>>>(Q0, Q1, WF, 2 * 48, NB_G);
    k_agg_dual<<<GA, 256, 0, stream>>>(Q0, Q1, col0, col1, rp0, rp1, dv0, dv1,
                                       fe_conv_b + 2 * 64, se_conv_b + 2 * 64, P0, P1, NT_AGG, 0);

    // ---- fused fusion-MLP + heads (scalar, R7-exact) ----
    k_tail<<<NB_ROW, 256, 0, stream>>>(P0, P1, fus_w1, fus_b1, fus_w2, fus_b2,
                                       out_w, out_b, cls_w, cls_b, (float*)d_out, N);
}